// Round 1
// baseline (196.320 us; speedup 1.0000x reference)
//
#include <hip/hip_runtime.h>

typedef __bf16 bf16x8 __attribute__((ext_vector_type(8)));
typedef float f32x4 __attribute__((ext_vector_type(4)));
typedef unsigned short u16;
typedef unsigned int u32;

#define AS1 __attribute__((address_space(1)))
#define AS3 __attribute__((address_space(3)))

__device__ __forceinline__ u16 f2bf(float f) {
  u32 u = __builtin_bit_cast(u32, f);
  u32 r = u + 0x7FFFu + ((u >> 16) & 1u);
  return (u16)(r >> 16);
}

__device__ __forceinline__ void gload_lds16(const void* g, void* l) {
  __builtin_amdgcn_global_load_lds((AS1 void*)(void*)g, (AS3 void*)l, 16, 0, 0);
}

__device__ __forceinline__ f32x4 mfma16(bf16x8 a, bf16x8 b, f32x4 c) {
  return __builtin_amdgcn_mfma_f32_16x16x32_bf16(a, b, c, 0, 0, 0);
}

// ---------------- fp32 -> bf16 convert ----------------
__global__ void k_f2bf(const float* __restrict__ src, u16* __restrict__ dst, int n4) {
  int i = blockIdx.x * blockDim.x + threadIdx.x;
  int stride = gridDim.x * blockDim.x;
  for (; i < n4; i += stride) {
    float4 v = reinterpret_cast<const float4*>(src)[i];
    ushort4 o;
    o.x = f2bf(v.x); o.y = f2bf(v.y); o.z = f2bf(v.z); o.w = f2bf(v.w);
    reinterpret_cast<ushort4*>(dst)[i] = o;
  }
}

// ---------------- GEMM: C[m][n] = A[m][:] . B[n][:] + bias[n] ----------------
// A: [M][K] bf16 row-major, B: [N][K] bf16 row-major (torch Linear weight layout)
// EPI 0: bf16 out; cols < 1024 (the q part) scaled by 0.125*log2(e) after bias
// EPI 1: fp32 out + bias
template<int BM, int BN, int EPI>
__global__ __launch_bounds__(256, 2)
void k_gemm_bt(const u16* __restrict__ A, const u16* __restrict__ B,
               const float* __restrict__ bias, void* __restrict__ out,
               int M, int N, int K)
{
  __shared__ __align__(16) u16 sA[BM * 32];
  __shared__ __align__(16) u16 sB[BN * 32];
  const int tid = threadIdx.x;
  const int lane = tid & 63;
  const int wid = tid >> 6;
  const int wm = wid >> 1, wn = wid & 1;
  const int bm0 = blockIdx.y * BM;
  const int bn0 = blockIdx.x * BN;
  constexpr int FM = BM / 32;
  constexpr int FN = BN / 32;

  f32x4 acc[FM][FN];
#pragma unroll
  for (int i = 0; i < FM; ++i)
#pragma unroll
    for (int j = 0; j < FN; ++j)
      acc[i][j] = (f32x4){0.f, 0.f, 0.f, 0.f};

  constexpr int CA = BM / 16;  // number of 1KB chunks in A tile (BM*64B)
  constexpr int CB = BN / 16;
  const int nk = K >> 5;
  for (int kt = 0; kt < nk; ++kt) {
    __syncthreads();
    const char* gA = (const char*)(A + (size_t)bm0 * K + kt * 32);
#pragma unroll
    for (int c = 0; c < CA / 4; ++c) {
      int ch = c * 4 + wid;
      int o = ch * 1024 + lane * 16;
      gload_lds16(gA + (size_t)(o >> 6) * (K * 2) + (o & 63), (char*)sA + ch * 1024);
    }
    const char* gB = (const char*)(B + (size_t)bn0 * K + kt * 32);
#pragma unroll
    for (int c = 0; c < CB / 4; ++c) {
      int ch = c * 4 + wid;
      int o = ch * 1024 + lane * 16;
      gload_lds16(gB + (size_t)(o >> 6) * (K * 2) + (o & 63), (char*)sB + ch * 1024);
    }
    __syncthreads();
    bf16x8 af[FM], bf[FN];
#pragma unroll
    for (int mi = 0; mi < FM; ++mi) {
      int row = wm * (BM / 2) + mi * 16 + (lane & 15);
      af[mi] = *(const bf16x8*)((const char*)sA + row * 64 + ((lane >> 4) << 4));
    }
#pragma unroll
    for (int ni = 0; ni < FN; ++ni) {
      int row = wn * (BN / 2) + ni * 16 + (lane & 15);
      bf[ni] = *(const bf16x8*)((const char*)sB + row * 64 + ((lane >> 4) << 4));
    }
#pragma unroll
    for (int mi = 0; mi < FM; ++mi)
#pragma unroll
      for (int ni = 0; ni < FN; ++ni)
        acc[mi][ni] = mfma16(af[mi], bf[ni], acc[mi][ni]);
  }

#pragma unroll
  for (int mi = 0; mi < FM; ++mi)
#pragma unroll
    for (int ni = 0; ni < FN; ++ni) {
      int row = bm0 + wm * (BM / 2) + mi * 16 + ((lane >> 4) << 2);
      int col = bn0 + wn * (BN / 2) + ni * 16 + (lane & 15);
      float bv = bias[col];
      if (EPI == 0) {
        float sc = (col < 1024) ? 0.18033688011112042f : 1.0f;  // 0.125*log2(e)
        u16* O = (u16*)out;
#pragma unroll
        for (int r = 0; r < 4; ++r)
          O[(size_t)(row + r) * N + col] = f2bf((acc[mi][ni][r] + bv) * sc);
      } else {
        float* O = (float*)out;
#pragma unroll
        for (int r = 0; r < 4; ++r)
          O[(size_t)(row + r) * N + col] = acc[mi][ni][r] + bv;
      }
    }
}

// ---------------- V transpose: qkv v-part [B,T,H,D] -> Vt[B*H][D=64][T=2048] ----------------
__global__ __launch_bounds__(256)
void k_vtrans(const u16* __restrict__ qkv, u16* __restrict__ vt)
{
  __shared__ __align__(16) u16 sT[64 * 72];
  const int tid = threadIdx.x;
  const int bh = blockIdx.y;
  const int b = bh >> 4, h = bh & 15;
  const int t0 = blockIdx.x * 64;
#pragma unroll
  for (int i = 0; i < 2; ++i) {
    int idx = i * 256 + tid;
    int r = idx >> 3, c = idx & 7;
    const u16* src = qkv + (size_t)(b * 2048 + t0 + r) * 3072 + 2048 + h * 64 + c * 8;
    *(uint4*)(sT + r * 72 + c * 8) = *(const uint4*)src;
  }
  __syncthreads();
#pragma unroll
  for (int i = 0; i < 2; ++i) {
    int idx = i * 256 + tid;
    int d = idx >> 3, tc = idx & 7;
    __align__(16) u16 vbuf[8];
#pragma unroll
    for (int j = 0; j < 8; ++j) vbuf[j] = sT[(tc * 8 + j) * 72 + d];
    *(uint4*)(vt + (size_t)(bh * 64 + d) * 2048 + t0 + tc * 8) = *(const uint4*)vbuf;
  }
}

// ---------------- fused causal flash attention ----------------
// qkv: [4096][3072] bf16 (q pre-scaled by 0.125*log2e), vt: [B*H][64][2048] bf16
// yb: [B,T,C] bf16 output (already in [b][t][h*64+d] layout for the out-proj GEMM)
__global__ __launch_bounds__(256, 2)
void k_attn(const u16* __restrict__ qkv, const u16* __restrict__ vt, u16* __restrict__ yb)
{
  __shared__ __align__(16) u16 sK[64 * 64];     // [kv][d], chunk-swizzled
  __shared__ __align__(16) u16 sV[64 * 64];     // [d][kv] (transposed V), chunk-swizzled
  __shared__ __align__(16) u16 sP[4][32 * 64];  // per-wave P, chunk-swizzled
  const int tid = threadIdx.x;
  const int lane = tid & 63;
  const int wid = tid >> 6;
  const int bh = blockIdx.y;
  const int b = bh >> 4, h = bh & 15;
  const int q0 = blockIdx.x * 128;
  const int wq0 = q0 + wid * 32;
  const int l15 = lane & 15;
  const int l4 = lane >> 4;

  // Q fragments (held in registers across the whole kv loop)
  bf16x8 qf[2][2];
#pragma unroll
  for (int qi = 0; qi < 2; ++qi)
#pragma unroll
    for (int ks = 0; ks < 2; ++ks) {
      const u16* src = qkv + (size_t)(b * 2048 + wq0 + qi * 16 + l15) * 3072 + h * 64 + ks * 32 + (l4 << 3);
      qf[qi][ks] = *(const bf16x8*)src;
    }

  f32x4 oacc[2][4];
  float m[2][4], lsum[2][4];
#pragma unroll
  for (int qi = 0; qi < 2; ++qi) {
#pragma unroll
    for (int di = 0; di < 4; ++di) oacc[qi][di] = (f32x4){0.f, 0.f, 0.f, 0.f};
#pragma unroll
    for (int r = 0; r < 4; ++r) { m[qi][r] = -1e30f; lsum[qi][r] = 0.f; }
  }

  const int nt = (q0 >> 6) + 2;
  for (int t = 0; t < nt; ++t) {
    const int kv0 = t * 64;
    __syncthreads();
    {
      const char* gK = (const char*)(qkv + (size_t)(b * 2048 + kv0) * 3072 + 1024 + h * 64);
      const char* gV = (const char*)(vt + (size_t)bh * 64 * 2048 + kv0);
#pragma unroll
      for (int i = 0; i < 2; ++i) {
        int ch = wid * 2 + i;
        int o = ch * 1024 + lane * 16;
        int row = o >> 7;
        int cs = ((o >> 4) & 7) ^ (row & 7);  // pre-swizzled global source chunk
        gload_lds16(gK + (size_t)row * 6144 + cs * 16, (char*)sK + ch * 1024);
        gload_lds16(gV + (size_t)row * 4096 + cs * 16, (char*)sV + ch * 1024);
      }
    }
    __syncthreads();
    const bool active = (kv0 <= wq0 + 31);
    if (active) {
      f32x4 s[2][4];
#pragma unroll
      for (int qi = 0; qi < 2; ++qi)
#pragma unroll
        for (int ki = 0; ki < 4; ++ki) s[qi][ki] = (f32x4){0.f, 0.f, 0.f, 0.f};
#pragma unroll
      for (int ks = 0; ks < 2; ++ks) {
        bf16x8 bk[4];
#pragma unroll
        for (int ki = 0; ki < 4; ++ki) {
          int row = ki * 16 + l15;
          int cc = (ks * 4 + l4) ^ (row & 7);
          bk[ki] = *(const bf16x8*)((const char*)sK + row * 128 + cc * 16);
        }
#pragma unroll
        for (int qi = 0; qi < 2; ++qi)
#pragma unroll
          for (int ki = 0; ki < 4; ++ki)
            s[qi][ki] = mfma16(qf[qi][ks], bk[ki], s[qi][ki]);
      }
      if (kv0 + 63 > wq0) {  // causal mask needed for this wave
#pragma unroll
        for (int qi = 0; qi < 2; ++qi)
#pragma unroll
          for (int r = 0; r < 4; ++r) {
            int rowq = wq0 + qi * 16 + (l4 << 2) + r;
#pragma unroll
            for (int ki = 0; ki < 4; ++ki) {
              int col = kv0 + ki * 16 + l15;
              if (col > rowq) s[qi][ki][r] = -1e30f;
            }
          }
      }
      // online softmax (base-2; scale folded into q)
      char* pw = (char*)sP[wid];
#pragma unroll
      for (int qi = 0; qi < 2; ++qi)
#pragma unroll
        for (int r = 0; r < 4; ++r) {
          float rm = fmaxf(fmaxf(s[qi][0][r], s[qi][1][r]), fmaxf(s[qi][2][r], s[qi][3][r]));
          rm = fmaxf(rm, __shfl_xor(rm, 1));
          rm = fmaxf(rm, __shfl_xor(rm, 2));
          rm = fmaxf(rm, __shfl_xor(rm, 4));
          rm = fmaxf(rm, __shfl_xor(rm, 8));
          float mn = fmaxf(m[qi][r], rm);
          float f = exp2f(m[qi][r] - mn);
          m[qi][r] = mn;
          float rs = 0.f;
#pragma unroll
          for (int ki = 0; ki < 4; ++ki) {
            float p = exp2f(s[qi][ki][r] - mn);
            s[qi][ki][r] = p;
            rs += p;
          }
          rs += __shfl_xor(rs, 1);
          rs += __shfl_xor(rs, 2);
          rs += __shfl_xor(rs, 4);
          rs += __shfl_xor(rs, 8);
          lsum[qi][r] = lsum[qi][r] * f + rs;
#pragma unroll
          for (int di = 0; di < 4; ++di) oacc[qi][di][r] *= f;
        }
      // write P (bf16) to per-wave LDS, swizzled
#pragma unroll
      for (int qi = 0; qi < 2; ++qi)
#pragma unroll
        for (int ki = 0; ki < 4; ++ki) {
          int col = ki * 16 + l15;
#pragma unroll
          for (int r = 0; r < 4; ++r) {
            int prow = qi * 16 + (l4 << 2) + r;
            int cc = (col >> 3) ^ (prow & 7);
            *(u16*)(pw + prow * 128 + cc * 16 + (col & 7) * 2) = f2bf(s[qi][ki][r]);
          }
        }
    }
    __syncthreads();
    if (active) {
      const char* pw = (const char*)sP[wid];
#pragma unroll
      for (int ks = 0; ks < 2; ++ks) {
        bf16x8 pa[2];
#pragma unroll
        for (int qi = 0; qi < 2; ++qi) {
          int row = qi * 16 + l15;
          int cc = (ks * 4 + l4) ^ (row & 7);
          pa[qi] = *(const bf16x8*)(pw + row * 128 + cc * 16);
        }
#pragma unroll
        for (int di = 0; di < 4; ++di) {
          int row = di * 16 + l15;
          int cc = (ks * 4 + l4) ^ (row & 7);
          bf16x8 bv = *(const bf16x8*)((const char*)sV + row * 128 + cc * 16);
#pragma unroll
          for (int qi = 0; qi < 2; ++qi)
            oacc[qi][di] = mfma16(pa[qi], bv, oacc[qi][di]);
        }
      }
    }
  }
  // epilogue: normalize and store to [b][t][h*64+d]
#pragma unroll
  for (int qi = 0; qi < 2; ++qi)
#pragma unroll
    for (int r = 0; r < 4; ++r) {
      float inv = 1.f / lsum[qi][r];
      size_t rowb = (size_t)(b * 2048 + wq0 + qi * 16 + (l4 << 2) + r) * 1024 + h * 64;
#pragma unroll
      for (int di = 0; di < 4; ++di)
        yb[rowb + di * 16 + l15] = f2bf(oacc[qi][di][r] * inv);
    }
}

extern "C" void kernel_launch(void* const* d_in, const int* in_sizes, int n_in,
                              void* d_out, int out_size, void* d_ws, size_t ws_size,
                              hipStream_t stream)
{
  (void)in_sizes; (void)n_in; (void)out_size; (void)ws_size;
  const float* x      = (const float*)d_in[0];
  const float* w_attn = (const float*)d_in[1];
  const float* b_attn = (const float*)d_in[2];
  const float* w_proj = (const float*)d_in[3];
  const float* b_proj = (const float*)d_in[4];
  float* out = (float*)d_out;
  char* ws = (char*)d_ws;
  u16* xb  = (u16*)(ws);                 // 4096x1024 bf16
  u16* wab = (u16*)(ws + 8388608);       // 3072x1024 bf16
  u16* wpb = (u16*)(ws + 14680064);      // 1024x1024 bf16
  u16* qkv = (u16*)(ws + 16777216);      // 4096x3072 bf16
  u16* vt  = (u16*)(ws + 41943040);      // 32x64x2048 bf16
  u16* yb  = (u16*)(ws + 50331648);      // 4096x1024 bf16

  k_f2bf<<<1024, 256, 0, stream>>>(x, xb, 4096 * 1024 / 4);
  k_f2bf<<<1024, 256, 0, stream>>>(w_attn, wab, 3072 * 1024 / 4);
  k_f2bf<<<1024, 256, 0, stream>>>(w_proj, wpb, 1024 * 1024 / 4);
  k_gemm_bt<128, 128, 0><<<dim3(24, 32), 256, 0, stream>>>(xb, wab, b_attn, qkv, 4096, 3072, 1024);
  k_vtrans<<<dim3(32, 32), 256, 0, stream>>>(qkv, vt);
  k_attn<<<dim3(16, 32), 256, 0, stream>>>(qkv, vt, yb);
  k_gemm_bt<64, 128, 1><<<dim3(8, 64), 256, 0, stream>>>(yb, wpb, b_proj, out, 4096, 1024, 1024);
}

// Round 2
// 175.125 us; speedup vs baseline: 1.1210x; 1.1210x over previous
//
#include <hip/hip_runtime.h>

typedef __bf16 bf16x8 __attribute__((ext_vector_type(8)));
typedef float f32x4 __attribute__((ext_vector_type(4)));
typedef unsigned short u16;
typedef unsigned int u32;

#define AS1 __attribute__((address_space(1)))
#define AS3 __attribute__((address_space(3)))

__device__ __forceinline__ u16 f2bf(float f) {
  u32 u = __builtin_bit_cast(u32, f);
  u32 r = u + 0x7FFFu + ((u >> 16) & 1u);
  return (u16)(r >> 16);
}

__device__ __forceinline__ void gload_lds16(const void* g, void* l) {
  __builtin_amdgcn_global_load_lds((AS1 void*)(void*)g, (AS3 void*)l, 16, 0, 0);
}

__device__ __forceinline__ f32x4 mfma16(bf16x8 a, bf16x8 b, f32x4 c) {
  return __builtin_amdgcn_mfma_f32_16x16x32_bf16(a, b, c, 0, 0, 0);
}

// ---------------- fp32 -> bf16 convert ----------------
__global__ void k_f2bf(const float* __restrict__ src, u16* __restrict__ dst, int n4) {
  int i = blockIdx.x * blockDim.x + threadIdx.x;
  int stride = gridDim.x * blockDim.x;
  for (; i < n4; i += stride) {
    float4 v = reinterpret_cast<const float4*>(src)[i];
    ushort4 o;
    o.x = f2bf(v.x); o.y = f2bf(v.y); o.z = f2bf(v.z); o.w = f2bf(v.w);
    reinterpret_cast<ushort4*>(dst)[i] = o;
  }
}

// ---------------- GEMM: C[m][n] = A[m][:] . B[n][:] + bias[n] ----------------
// A: [M][K] bf16 row-major, B: [N][K] bf16 row-major (torch Linear weight layout)
// EPI 0: bf16 out; cols < 1024 (the q part) scaled by 0.125*log2(e) after bias
// EPI 1: fp32 out + bias
template<int BM, int BN, int EPI>
__global__ __launch_bounds__(256, 2)
void k_gemm_bt(const u16* __restrict__ A, const u16* __restrict__ B,
               const float* __restrict__ bias, void* __restrict__ out,
               int M, int N, int K)
{
  __shared__ __align__(16) u16 sA[BM * 32];
  __shared__ __align__(16) u16 sB[BN * 32];
  const int tid = threadIdx.x;
  const int lane = tid & 63;
  const int wid = tid >> 6;
  const int wm = wid >> 1, wn = wid & 1;
  const int bm0 = blockIdx.y * BM;
  const int bn0 = blockIdx.x * BN;
  constexpr int FM = BM / 32;
  constexpr int FN = BN / 32;

  f32x4 acc[FM][FN];
#pragma unroll
  for (int i = 0; i < FM; ++i)
#pragma unroll
    for (int j = 0; j < FN; ++j)
      acc[i][j] = (f32x4){0.f, 0.f, 0.f, 0.f};

  constexpr int CA = BM / 16;  // number of 1KB chunks in A tile (BM*64B)
  constexpr int CB = BN / 16;
  const int nk = K >> 5;
  for (int kt = 0; kt < nk; ++kt) {
    __syncthreads();
    const char* gA = (const char*)(A + (size_t)bm0 * K + kt * 32);
#pragma unroll
    for (int c = 0; c < CA / 4; ++c) {
      int ch = c * 4 + wid;
      int o = ch * 1024 + lane * 16;
      gload_lds16(gA + (size_t)(o >> 6) * (K * 2) + (o & 63), (char*)sA + ch * 1024);
    }
    const char* gB = (const char*)(B + (size_t)bn0 * K + kt * 32);
#pragma unroll
    for (int c = 0; c < CB / 4; ++c) {
      int ch = c * 4 + wid;
      int o = ch * 1024 + lane * 16;
      gload_lds16(gB + (size_t)(o >> 6) * (K * 2) + (o & 63), (char*)sB + ch * 1024);
    }
    __syncthreads();
    bf16x8 af[FM], bf[FN];
#pragma unroll
    for (int mi = 0; mi < FM; ++mi) {
      int row = wm * (BM / 2) + mi * 16 + (lane & 15);
      af[mi] = *(const bf16x8*)((const char*)sA + row * 64 + ((lane >> 4) << 4));
    }
#pragma unroll
    for (int ni = 0; ni < FN; ++ni) {
      int row = wn * (BN / 2) + ni * 16 + (lane & 15);
      bf[ni] = *(const bf16x8*)((const char*)sB + row * 64 + ((lane >> 4) << 4));
    }
#pragma unroll
    for (int mi = 0; mi < FM; ++mi)
#pragma unroll
      for (int ni = 0; ni < FN; ++ni)
        acc[mi][ni] = mfma16(af[mi], bf[ni], acc[mi][ni]);
  }

#pragma unroll
  for (int mi = 0; mi < FM; ++mi)
#pragma unroll
    for (int ni = 0; ni < FN; ++ni) {
      int row = bm0 + wm * (BM / 2) + mi * 16 + ((lane >> 4) << 2);
      int col = bn0 + wn * (BN / 2) + ni * 16 + (lane & 15);
      float bv = bias[col];
      if (EPI == 0) {
        float sc = (col < 1024) ? 0.18033688011112042f : 1.0f;  // 0.125*log2(e)
        u16* O = (u16*)out;
#pragma unroll
        for (int r = 0; r < 4; ++r)
          O[(size_t)(row + r) * N + col] = f2bf((acc[mi][ni][r] + bv) * sc);
      } else {
        float* O = (float*)out;
#pragma unroll
        for (int r = 0; r < 4; ++r)
          O[(size_t)(row + r) * N + col] = acc[mi][ni][r] + bv;
      }
    }
}

// ---------------- V transpose: qkv v-part [B,T,H,D] -> Vt[B*H][D=64][T=2048] ----------------
__global__ __launch_bounds__(256)
void k_vtrans(const u16* __restrict__ qkv, u16* __restrict__ vt)
{
  __shared__ __align__(16) u16 sT[64 * 72];
  const int tid = threadIdx.x;
  const int bh = blockIdx.y;
  const int b = bh >> 4, h = bh & 15;
  const int t0 = blockIdx.x * 64;
#pragma unroll
  for (int i = 0; i < 2; ++i) {
    int idx = i * 256 + tid;
    int r = idx >> 3, c = idx & 7;
    const u16* src = qkv + (size_t)(b * 2048 + t0 + r) * 3072 + 2048 + h * 64 + c * 8;
    *(uint4*)(sT + r * 72 + c * 8) = *(const uint4*)src;
  }
  __syncthreads();
#pragma unroll
  for (int i = 0; i < 2; ++i) {
    int idx = i * 256 + tid;
    int d = idx >> 3, tc = idx & 7;
    __align__(16) u16 vbuf[8];
#pragma unroll
    for (int j = 0; j < 8; ++j) vbuf[j] = sT[(tc * 8 + j) * 72 + d];
    *(uint4*)(vt + (size_t)(bh * 64 + d) * 2048 + t0 + tc * 8) = *(const uint4*)vbuf;
  }
}

// ---------------- fused causal flash attention ----------------
// qkv: [4096][3072] bf16 (q pre-scaled by 0.125*log2e), vt: [B*H][64][2048] bf16
// yb: [B,T,C] bf16 output. Double-buffered K/V staging, one barrier per kv tile.
// Grid: 512 1D blocks; bid c and c+256 get complementary qtiles (load balance).
__global__ __launch_bounds__(256, 2)
void k_attn(const u16* __restrict__ qkv, const u16* __restrict__ vt, u16* __restrict__ yb)
{
  __shared__ __align__(16) u16 sK[2][64 * 64];   // [kv][d], chunk-swizzled
  __shared__ __align__(16) u16 sV[2][64 * 64];   // [d][kv] (transposed V), chunk-swizzled
  __shared__ __align__(16) u16 sP[4][32 * 64];   // per-wave P, chunk-swizzled
  const int tid = threadIdx.x;
  const int lane = tid & 63;
  const int wid = tid >> 6;
  // balanced remap: bid and bid+256 land on the same CU (round-robin heuristic)
  // and get complementary qtiles -> equal work per CU.
  const int bid = blockIdx.x;
  const int half = bid >> 8;
  const int u = bid & 255;
  const int bh = u >> 3;
  const int qs = u & 7;
  const int qtile = half ? (15 - qs) : qs;
  const int b = bh >> 4, h = bh & 15;
  const int q0 = qtile * 128;
  const int wq0 = q0 + wid * 32;
  const int l15 = lane & 15;
  const int l4 = lane >> 4;

  // Q fragments (held in registers across the whole kv loop)
  bf16x8 qf[2][2];
#pragma unroll
  for (int qi = 0; qi < 2; ++qi)
#pragma unroll
    for (int ks = 0; ks < 2; ++ks) {
      const u16* src = qkv + (size_t)(b * 2048 + wq0 + qi * 16 + l15) * 3072 + h * 64 + ks * 32 + (l4 << 3);
      qf[qi][ks] = *(const bf16x8*)src;
    }

  f32x4 oacc[2][4];
  float m[2][4], lsum[2][4];
#pragma unroll
  for (int qi = 0; qi < 2; ++qi) {
#pragma unroll
    for (int di = 0; di < 4; ++di) oacc[qi][di] = (f32x4){0.f, 0.f, 0.f, 0.f};
#pragma unroll
    for (int r = 0; r < 4; ++r) { m[qi][r] = -1e30f; lsum[qi][r] = 0.f; }
  }

  auto stage = [&](int kv0, int buf) {
    const char* gK = (const char*)(qkv + (size_t)(b * 2048 + kv0) * 3072 + 1024 + h * 64);
    const char* gV = (const char*)(vt + (size_t)bh * 131072 + kv0);
#pragma unroll
    for (int i = 0; i < 2; ++i) {
      int ch = wid * 2 + i;
      int o = ch * 1024 + lane * 16;
      int row = o >> 7;
      int cs = ((o >> 4) & 7) ^ (row & 7);  // pre-swizzled global source chunk
      gload_lds16(gK + (size_t)row * 6144 + cs * 16, (char*)sK[buf] + ch * 1024);
      gload_lds16(gV + (size_t)row * 4096 + cs * 16, (char*)sV[buf] + ch * 1024);
    }
  };

  const int nt = (q0 >> 6) + 2;
  int cur = 0;
  stage(0, 0);
  __syncthreads();
  for (int t = 0; t < nt; ++t) {
    const int kv0 = t * 64;
    if (t + 1 < nt) stage((t + 1) * 64, cur ^ 1);  // prefetch next tile (drains at barrier)
    const bool active = (kv0 <= wq0 + 31);
    if (active) {
      f32x4 s[2][4];
#pragma unroll
      for (int qi = 0; qi < 2; ++qi)
#pragma unroll
        for (int ki = 0; ki < 4; ++ki) s[qi][ki] = (f32x4){0.f, 0.f, 0.f, 0.f};
#pragma unroll
      for (int ks = 0; ks < 2; ++ks) {
        bf16x8 bk[4];
#pragma unroll
        for (int ki = 0; ki < 4; ++ki) {
          int row = ki * 16 + l15;
          int cc = (ks * 4 + l4) ^ (row & 7);
          bk[ki] = *(const bf16x8*)((const char*)sK[cur] + row * 128 + cc * 16);
        }
#pragma unroll
        for (int qi = 0; qi < 2; ++qi)
#pragma unroll
          for (int ki = 0; ki < 4; ++ki)
            s[qi][ki] = mfma16(qf[qi][ks], bk[ki], s[qi][ki]);
      }
      if (kv0 + 63 > wq0) {  // causal mask needed for this wave
#pragma unroll
        for (int qi = 0; qi < 2; ++qi)
#pragma unroll
          for (int r = 0; r < 4; ++r) {
            int rowq = wq0 + qi * 16 + (l4 << 2) + r;
#pragma unroll
            for (int ki = 0; ki < 4; ++ki) {
              int col = kv0 + ki * 16 + l15;
              if (col > rowq) s[qi][ki][r] = -1e30f;
            }
          }
      }
      // online softmax (base-2; scale folded into q)
      char* pw = (char*)sP[wid];
#pragma unroll
      for (int qi = 0; qi < 2; ++qi)
#pragma unroll
        for (int r = 0; r < 4; ++r) {
          float rm = fmaxf(fmaxf(s[qi][0][r], s[qi][1][r]), fmaxf(s[qi][2][r], s[qi][3][r]));
          rm = fmaxf(rm, __shfl_xor(rm, 1));
          rm = fmaxf(rm, __shfl_xor(rm, 2));
          rm = fmaxf(rm, __shfl_xor(rm, 4));
          rm = fmaxf(rm, __shfl_xor(rm, 8));
          float mn = fmaxf(m[qi][r], rm);
          float f = exp2f(m[qi][r] - mn);
          m[qi][r] = mn;
          float rs = 0.f;
#pragma unroll
          for (int ki = 0; ki < 4; ++ki) {
            float p = exp2f(s[qi][ki][r] - mn);
            s[qi][ki][r] = p;
            rs += p;
          }
          rs += __shfl_xor(rs, 1);
          rs += __shfl_xor(rs, 2);
          rs += __shfl_xor(rs, 4);
          rs += __shfl_xor(rs, 8);
          lsum[qi][r] = lsum[qi][r] * f + rs;
#pragma unroll
          for (int di = 0; di < 4; ++di) oacc[qi][di][r] *= f;
        }
      // write P (bf16) to per-wave LDS, swizzled. Same-wave producer/consumer:
      // no barrier needed, compiler inserts the lgkmcnt wait.
#pragma unroll
      for (int qi = 0; qi < 2; ++qi)
#pragma unroll
        for (int ki = 0; ki < 4; ++ki) {
          int col = ki * 16 + l15;
#pragma unroll
          for (int r = 0; r < 4; ++r) {
            int prow = qi * 16 + (l4 << 2) + r;
            int cc = (col >> 3) ^ (prow & 7);
            *(u16*)(pw + prow * 128 + cc * 16 + (col & 7) * 2) = f2bf(s[qi][ki][r]);
          }
        }
      const char* pwc = (const char*)sP[wid];
#pragma unroll
      for (int ks = 0; ks < 2; ++ks) {
        bf16x8 pa[2];
#pragma unroll
        for (int qi = 0; qi < 2; ++qi) {
          int row = qi * 16 + l15;
          int cc = (ks * 4 + l4) ^ (row & 7);
          pa[qi] = *(const bf16x8*)(pwc + row * 128 + cc * 16);
        }
#pragma unroll
        for (int di = 0; di < 4; ++di) {
          int row = di * 16 + l15;
          int cc = (ks * 4 + l4) ^ (row & 7);
          bf16x8 bv = *(const bf16x8*)((const char*)sV[cur] + row * 128 + cc * 16);
#pragma unroll
          for (int qi = 0; qi < 2; ++qi)
            oacc[qi][di] = mfma16(pa[qi], bv, oacc[qi][di]);
        }
      }
    }
    __syncthreads();  // drains vmcnt(0): publishes buf[cur^1] for next iteration
    cur ^= 1;
  }
  // epilogue: normalize and store to [b][t][h*64+d]
#pragma unroll
  for (int qi = 0; qi < 2; ++qi)
#pragma unroll
    for (int r = 0; r < 4; ++r) {
      float inv = 1.f / lsum[qi][r];
      size_t rowb = (size_t)(b * 2048 + wq0 + qi * 16 + (l4 << 2) + r) * 1024 + h * 64;
#pragma unroll
      for (int di = 0; di < 4; ++di)
        yb[rowb + di * 16 + l15] = f2bf(oacc[qi][di][r] * inv);
    }
}

extern "C" void kernel_launch(void* const* d_in, const int* in_sizes, int n_in,
                              void* d_out, int out_size, void* d_ws, size_t ws_size,
                              hipStream_t stream)
{
  (void)in_sizes; (void)n_in; (void)out_size; (void)ws_size;
  const float* x      = (const float*)d_in[0];
  const float* w_attn = (const float*)d_in[1];
  const float* b_attn = (const float*)d_in[2];
  const float* w_proj = (const float*)d_in[3];
  const float* b_proj = (const float*)d_in[4];
  float* out = (float*)d_out;
  char* ws = (char*)d_ws;
  u16* xb  = (u16*)(ws);                 // 4096x1024 bf16
  u16* wab = (u16*)(ws + 8388608);       // 3072x1024 bf16
  u16* wpb = (u16*)(ws + 14680064);      // 1024x1024 bf16
  u16* qkv = (u16*)(ws + 16777216);      // 4096x3072 bf16
  u16* vt  = (u16*)(ws + 41943040);      // 32x64x2048 bf16
  u16* yb  = (u16*)(ws + 50331648);      // 4096x1024 bf16

  k_f2bf<<<1024, 256, 0, stream>>>(x, xb, 4096 * 1024 / 4);
  k_f2bf<<<1024, 256, 0, stream>>>(w_attn, wab, 3072 * 1024 / 4);
  k_f2bf<<<1024, 256, 0, stream>>>(w_proj, wpb, 1024 * 1024 / 4);
  k_gemm_bt<128, 128, 0><<<dim3(24, 32), 256, 0, stream>>>(xb, wab, b_attn, qkv, 4096, 3072, 1024);
  k_vtrans<<<dim3(32, 32), 256, 0, stream>>>(qkv, vt);
  k_attn<<<512, 256, 0, stream>>>(qkv, vt, yb);
  k_gemm_bt<64, 128, 1><<<dim3(8, 64), 256, 0, stream>>>(yb, wpb, b_proj, out, 4096, 1024, 1024);
}

// Round 3
// 138.431 us; speedup vs baseline: 1.4182x; 1.2651x over previous
//
#include <hip/hip_runtime.h>

typedef __bf16 bf16x8 __attribute__((ext_vector_type(8)));
typedef float f32x4 __attribute__((ext_vector_type(4)));
typedef unsigned int u32x4 __attribute__((ext_vector_type(4)));
typedef unsigned short u16;
typedef unsigned int u32;

#define AS1 __attribute__((address_space(1)))
#define AS3 __attribute__((address_space(3)))

__device__ __forceinline__ u16 f2bf(float f) {
  u32 u = __builtin_bit_cast(u32, f);
  u32 r = u + 0x7FFFu + ((u >> 16) & 1u);
  return (u16)(r >> 16);
}

// packed f32x2 -> bf16x2 (RTNE), single instruction on gfx950
__device__ __forceinline__ u32 cvtpk(float lo, float hi) {
  u32 r;
  asm("v_cvt_pk_bf16_f32 %0, %1, %2" : "=v"(r) : "v"(lo), "v"(hi));
  return r;
}

__device__ __forceinline__ void gload_lds16(const void* g, void* l) {
  __builtin_amdgcn_global_load_lds((AS1 void*)(void*)g, (AS3 void*)l, 16, 0, 0);
}

__device__ __forceinline__ f32x4 mfma16(bf16x8 a, bf16x8 b, f32x4 c) {
  return __builtin_amdgcn_mfma_f32_16x16x32_bf16(a, b, c, 0, 0, 0);
}

// ---------------- fp32 -> bf16 convert ----------------
__global__ void k_f2bf(const float* __restrict__ src, u16* __restrict__ dst, int n4) {
  int i = blockIdx.x * blockDim.x + threadIdx.x;
  int stride = gridDim.x * blockDim.x;
  for (; i < n4; i += stride) {
    float4 v = reinterpret_cast<const float4*>(src)[i];
    ushort4 o;
    o.x = f2bf(v.x); o.y = f2bf(v.y); o.z = f2bf(v.z); o.w = f2bf(v.w);
    reinterpret_cast<ushort4*>(dst)[i] = o;
  }
}

// ---------------- GEMM: C[m][n] = A[m][:] . B[n][:] + bias[n] ----------------
template<int BM, int BN, int EPI>
__global__ __launch_bounds__(256, 2)
void k_gemm_bt(const u16* __restrict__ A, const u16* __restrict__ B,
               const float* __restrict__ bias, void* __restrict__ out,
               int M, int N, int K)
{
  __shared__ __align__(16) u16 sA[BM * 32];
  __shared__ __align__(16) u16 sB[BN * 32];
  const int tid = threadIdx.x;
  const int lane = tid & 63;
  const int wid = tid >> 6;
  const int wm = wid >> 1, wn = wid & 1;
  const int bm0 = blockIdx.y * BM;
  const int bn0 = blockIdx.x * BN;
  constexpr int FM = BM / 32;
  constexpr int FN = BN / 32;

  f32x4 acc[FM][FN];
#pragma unroll
  for (int i = 0; i < FM; ++i)
#pragma unroll
    for (int j = 0; j < FN; ++j)
      acc[i][j] = (f32x4){0.f, 0.f, 0.f, 0.f};

  constexpr int CA = BM / 16;
  constexpr int CB = BN / 16;
  const int nk = K >> 5;
  for (int kt = 0; kt < nk; ++kt) {
    __syncthreads();
    const char* gA = (const char*)(A + (size_t)bm0 * K + kt * 32);
#pragma unroll
    for (int c = 0; c < CA / 4; ++c) {
      int ch = c * 4 + wid;
      int o = ch * 1024 + lane * 16;
      gload_lds16(gA + (size_t)(o >> 6) * (K * 2) + (o & 63), (char*)sA + ch * 1024);
    }
    const char* gB = (const char*)(B + (size_t)bn0 * K + kt * 32);
#pragma unroll
    for (int c = 0; c < CB / 4; ++c) {
      int ch = c * 4 + wid;
      int o = ch * 1024 + lane * 16;
      gload_lds16(gB + (size_t)(o >> 6) * (K * 2) + (o & 63), (char*)sB + ch * 1024);
    }
    __syncthreads();
    bf16x8 af[FM], bf[FN];
#pragma unroll
    for (int mi = 0; mi < FM; ++mi) {
      int row = wm * (BM / 2) + mi * 16 + (lane & 15);
      af[mi] = *(const bf16x8*)((const char*)sA + row * 64 + ((lane >> 4) << 4));
    }
#pragma unroll
    for (int ni = 0; ni < FN; ++ni) {
      int row = wn * (BN / 2) + ni * 16 + (lane & 15);
      bf[ni] = *(const bf16x8*)((const char*)sB + row * 64 + ((lane >> 4) << 4));
    }
#pragma unroll
    for (int mi = 0; mi < FM; ++mi)
#pragma unroll
      for (int ni = 0; ni < FN; ++ni)
        acc[mi][ni] = mfma16(af[mi], bf[ni], acc[mi][ni]);
  }

#pragma unroll
  for (int mi = 0; mi < FM; ++mi)
#pragma unroll
    for (int ni = 0; ni < FN; ++ni) {
      int row = bm0 + wm * (BM / 2) + mi * 16 + ((lane >> 4) << 2);
      int col = bn0 + wn * (BN / 2) + ni * 16 + (lane & 15);
      float bv = bias[col];
      if (EPI == 0) {
        float sc = (col < 1024) ? 0.18033688011112042f : 1.0f;  // 0.125*log2(e)
        u16* O = (u16*)out;
#pragma unroll
        for (int r = 0; r < 4; ++r)
          O[(size_t)(row + r) * N + col] = f2bf((acc[mi][ni][r] + bv) * sc);
      } else {
        float* O = (float*)out;
#pragma unroll
        for (int r = 0; r < 4; ++r)
          O[(size_t)(row + r) * N + col] = acc[mi][ni][r] + bv;
      }
    }
}

// ---------------- V transpose: qkv v-part [B,T,H,D] -> Vt[B*H][64][2048] ----------------
// Column order within each 64-wide tile is PERMUTED so attention's PV B-fragment
// (built in-register from the swapped-QK^T S^T layout) contracts consistently:
// within-tile col' = g*4+r holds kv = 32*(g>>3) + 16*(g&1) + 4*((g>>1)&3) + r.
__global__ __launch_bounds__(256)
void k_vtrans(const u16* __restrict__ qkv, u16* __restrict__ vt)
{
  __shared__ __align__(16) u16 sT[64 * 72];
  const int tid = threadIdx.x;
  const int bh = blockIdx.y;
  const int b = bh >> 4, h = bh & 15;
  const int t0 = blockIdx.x * 64;
#pragma unroll
  for (int i = 0; i < 2; ++i) {
    int idx = i * 256 + tid;
    int r = idx >> 3, c = idx & 7;
    const u16* src = qkv + (size_t)(b * 2048 + t0 + r) * 3072 + 2048 + h * 64 + c * 8;
    *(uint4*)(sT + r * 72 + c * 8) = *(const uint4*)src;
  }
  __syncthreads();
#pragma unroll
  for (int i = 0; i < 4; ++i) {
    int idx = i * 256 + tid;       // 1024 (d,g) pairs
    int g = idx & 15;
    int d = idx >> 4;
    int kvb = 32 * (g >> 3) + 16 * (g & 1) + 4 * ((g >> 1) & 3);
    u16 v0 = sT[(kvb + 0) * 72 + d];
    u16 v1 = sT[(kvb + 1) * 72 + d];
    u16 v2 = sT[(kvb + 2) * 72 + d];
    u16 v3 = sT[(kvb + 3) * 72 + d];
    uint2 w;
    w.x = ((u32)v1 << 16) | v0;
    w.y = ((u32)v3 << 16) | v2;
    *(uint2*)(vt + (size_t)(bh * 64 + d) * 2048 + t0 + g * 4) = w;
  }
}

// ---------------- fused causal flash attention ----------------
// Swapped QK^T (S^T in registers: lane owns one q-row per qi), in-register
// softmax + P-pack (cvt_pk_bf16), PV via permuted-V fragments. No P LDS.
__global__ __launch_bounds__(256, 4)
void k_attn(const u16* __restrict__ qkv, const u16* __restrict__ vt, u16* __restrict__ yb)
{
  __shared__ __align__(16) u16 sK[2][64 * 64];   // [kv][d], chunk-swizzled
  __shared__ __align__(16) u16 sV[2][64 * 64];   // [d][kv'] (transposed+permuted V), chunk-swizzled
  const int tid = threadIdx.x;
  const int lane = tid & 63;
  const int wid = tid >> 6;
  const int bid = blockIdx.x;
  const int half = bid >> 8;
  const int u = bid & 255;
  const int bh = u >> 3;
  const int qs = u & 7;
  const int qtile = half ? (15 - qs) : qs;
  const int b = bh >> 4, h = bh & 15;
  const int q0 = qtile * 128;
  const int wq0 = q0 + wid * 32;
  const int l15 = lane & 15;
  const int l4 = lane >> 4;

  // Q fragments (B-operand of swapped QK^T): lane holds Q[q=wq0+qi*16+l15][32ks+l4*8..]
  bf16x8 qf[2][2];
#pragma unroll
  for (int qi = 0; qi < 2; ++qi)
#pragma unroll
    for (int ks = 0; ks < 2; ++ks) {
      const u16* src = qkv + (size_t)(b * 2048 + wq0 + qi * 16 + l15) * 3072 + h * 64 + ks * 32 + (l4 << 3);
      qf[qi][ks] = *(const bf16x8*)src;
    }

  f32x4 oacc[2][4];   // y^T: [q=qi*16+l15][d=di*16+l4*4+r]
  float m[2], lsum[2];
#pragma unroll
  for (int qi = 0; qi < 2; ++qi) {
#pragma unroll
    for (int di = 0; di < 4; ++di) oacc[qi][di] = (f32x4){0.f, 0.f, 0.f, 0.f};
    m[qi] = -1e30f; lsum[qi] = 0.f;
  }

  auto stage = [&](int kv0, int buf) {
    const char* gK = (const char*)(qkv + (size_t)(b * 2048 + kv0) * 3072 + 1024 + h * 64);
    const char* gV = (const char*)(vt + (size_t)bh * 131072 + kv0);
#pragma unroll
    for (int i = 0; i < 2; ++i) {
      int ch = wid * 2 + i;
      int o = ch * 1024 + lane * 16;
      int row = o >> 7;
      int cs = ((o >> 4) & 7) ^ (row & 7);  // pre-swizzled global source chunk
      gload_lds16(gK + (size_t)row * 6144 + cs * 16, (char*)sK[buf] + ch * 1024);
      gload_lds16(gV + (size_t)row * 4096 + cs * 16, (char*)sV[buf] + ch * 1024);
    }
  };

  const int nt = (q0 >> 6) + 2;
  int cur = 0;
  stage(0, 0);
  __syncthreads();
  for (int t = 0; t < nt; ++t) {
    const int kv0 = t * 64;
    if (t + 1 < nt) stage((t + 1) * 64, cur ^ 1);  // prefetch next tile (drains at barrier)
    const bool active = (kv0 <= wq0 + 31);
    if (active) {
      // ---- QK^T (swapped): s[qi][ki] = S^T, lane owns q=qi*16+l15, kv=ki*16+l4*4+r
      f32x4 s[2][4];
#pragma unroll
      for (int qi = 0; qi < 2; ++qi)
#pragma unroll
        for (int ki = 0; ki < 4; ++ki) s[qi][ki] = (f32x4){0.f, 0.f, 0.f, 0.f};
#pragma unroll
      for (int ks = 0; ks < 2; ++ks) {
        bf16x8 bk[4];
#pragma unroll
        for (int ki = 0; ki < 4; ++ki) {
          int row = ki * 16 + l15;
          int cc = (ks * 4 + l4) ^ (row & 7);
          bk[ki] = *(const bf16x8*)((const char*)sK[cur] + row * 128 + cc * 16);
        }
#pragma unroll
        for (int qi = 0; qi < 2; ++qi)
#pragma unroll
          for (int ki = 0; ki < 4; ++ki)
            s[qi][ki] = mfma16(bk[ki], qf[qi][ks], s[qi][ki]);
      }
      if (kv0 + 63 > wq0) {  // causal mask (boundary tiles only)
#pragma unroll
        for (int qi = 0; qi < 2; ++qi) {
          int qa = wq0 + qi * 16 + l15;
#pragma unroll
          for (int ki = 0; ki < 4; ++ki) {
            int kvb = kv0 + ki * 16 + l4 * 4;
#pragma unroll
            for (int rr = 0; rr < 4; ++rr)
              if (kvb + rr > qa) s[qi][ki][rr] = -1e30f;
          }
        }
      }
      // ---- online softmax, per-lane rows; defer-max (THR=8 in log2 domain)
      u32 pk_[2][4][2];
#pragma unroll
      for (int qi = 0; qi < 2; ++qi) {
        float rm = s[qi][0][0];
#pragma unroll
        for (int ki = 0; ki < 4; ++ki)
#pragma unroll
          for (int rr = 0; rr < 4; ++rr)
            rm = fmaxf(rm, s[qi][ki][rr]);
        rm = fmaxf(rm, __shfl_xor(rm, 16));
        rm = fmaxf(rm, __shfl_xor(rm, 32));
        float mo = m[qi];
        float mn;
        if (__all(rm <= mo + 8.f)) {
          mn = mo;  // stable: skip rescale, P bounded by 2^8
        } else {
          mn = fmaxf(mo, rm);
          float f = exp2f(mo - mn);
          m[qi] = mn;
          lsum[qi] *= f;
#pragma unroll
          for (int di = 0; di < 4; ++di)
#pragma unroll
            for (int rr = 0; rr < 4; ++rr)
              oacc[qi][di][rr] *= f;
        }
        float rs = 0.f;
#pragma unroll
        for (int ki = 0; ki < 4; ++ki) {
          float p0 = exp2f(s[qi][ki][0] - mn);
          float p1 = exp2f(s[qi][ki][1] - mn);
          float p2 = exp2f(s[qi][ki][2] - mn);
          float p3 = exp2f(s[qi][ki][3] - mn);
          rs += (p0 + p1) + (p2 + p3);
          pk_[qi][ki][0] = cvtpk(p0, p1);
          pk_[qi][ki][1] = cvtpk(p2, p3);
        }
        rs += __shfl_xor(rs, 16);
        rs += __shfl_xor(rs, 32);
        lsum[qi] += rs;
      }
      // ---- PV: oacc^T += V'^T-frag (A) x P-frag (B); V column permutation makes
      //      the k-index mapping identical on both operands.
#pragma unroll
      for (int ks = 0; ks < 2; ++ks) {
        u32x4 w0 = {pk_[0][2 * ks][0], pk_[0][2 * ks][1], pk_[0][2 * ks + 1][0], pk_[0][2 * ks + 1][1]};
        u32x4 w1 = {pk_[1][2 * ks][0], pk_[1][2 * ks][1], pk_[1][2 * ks + 1][0], pk_[1][2 * ks + 1][1]};
        bf16x8 pb0 = __builtin_bit_cast(bf16x8, w0);
        bf16x8 pb1 = __builtin_bit_cast(bf16x8, w1);
#pragma unroll
        for (int di = 0; di < 4; ++di) {
          int row = di * 16 + l15;
          int cc = (ks * 4 + l4) ^ (row & 7);
          bf16x8 bv = *(const bf16x8*)((const char*)sV[cur] + row * 128 + cc * 16);
          oacc[0][di] = mfma16(bv, pb0, oacc[0][di]);
          oacc[1][di] = mfma16(bv, pb1, oacc[1][di]);
        }
      }
    }
    __syncthreads();  // drains vmcnt(0): publishes buf[cur^1] for next iteration
    cur ^= 1;
  }
  // ---- epilogue: normalize, pack 4 consecutive d per store (8B)
#pragma unroll
  for (int qi = 0; qi < 2; ++qi) {
    float inv = 1.f / lsum[qi];
    size_t rowb = (size_t)(b * 2048 + wq0 + qi * 16 + l15) * 1024 + h * 64 + l4 * 4;
#pragma unroll
    for (int di = 0; di < 4; ++di) {
      uint2 w;
      w.x = cvtpk(oacc[qi][di][0] * inv, oacc[qi][di][1] * inv);
      w.y = cvtpk(oacc[qi][di][2] * inv, oacc[qi][di][3] * inv);
      *(uint2*)(yb + rowb + di * 16) = w;
    }
  }
}

extern "C" void kernel_launch(void* const* d_in, const int* in_sizes, int n_in,
                              void* d_out, int out_size, void* d_ws, size_t ws_size,
                              hipStream_t stream)
{
  (void)in_sizes; (void)n_in; (void)out_size; (void)ws_size;
  const float* x      = (const float*)d_in[0];
  const float* w_attn = (const float*)d_in[1];
  const float* b_attn = (const float*)d_in[2];
  const float* w_proj = (const float*)d_in[3];
  const float* b_proj = (const float*)d_in[4];
  float* out = (float*)d_out;
  char* ws = (char*)d_ws;
  u16* xb  = (u16*)(ws);                 // 4096x1024 bf16
  u16* wab = (u16*)(ws + 8388608);       // 3072x1024 bf16
  u16* wpb = (u16*)(ws + 14680064);      // 1024x1024 bf16
  u16* qkv = (u16*)(ws + 16777216);      // 4096x3072 bf16
  u16* vt  = (u16*)(ws + 41943040);      // 32x64x2048 bf16 (permuted cols)
  u16* yb  = (u16*)(ws + 50331648);      // 4096x1024 bf16

  k_f2bf<<<1024, 256, 0, stream>>>(x, xb, 4096 * 1024 / 4);
  k_f2bf<<<1024, 256, 0, stream>>>(w_attn, wab, 3072 * 1024 / 4);
  k_f2bf<<<1024, 256, 0, stream>>>(w_proj, wpb, 1024 * 1024 / 4);
  k_gemm_bt<128, 128, 0><<<dim3(24, 32), 256, 0, stream>>>(xb, wab, b_attn, qkv, 4096, 3072, 1024);
  k_vtrans<<<dim3(32, 32), 256, 0, stream>>>(qkv, vt);
  k_attn<<<512, 256, 0, stream>>>(qkv, vt, yb);
  k_gemm_bt<64, 128, 1><<<dim3(8, 64), 256, 0, stream>>>(yb, wpb, b_proj, out, 4096, 1024, 1024);
}

// Round 4
// 115.224 us; speedup vs baseline: 1.7038x; 1.2014x over previous
//
#include <hip/hip_runtime.h>

typedef __bf16 bf16x8 __attribute__((ext_vector_type(8)));
typedef float f32x4 __attribute__((ext_vector_type(4)));
typedef unsigned int u32x4 __attribute__((ext_vector_type(4)));
typedef unsigned short u16;
typedef unsigned int u32;

#define AS1 __attribute__((address_space(1)))
#define AS3 __attribute__((address_space(3)))

__device__ __forceinline__ u16 f2bf(float f) {
  u32 u = __builtin_bit_cast(u32, f);
  u32 r = u + 0x7FFFu + ((u >> 16) & 1u);
  return (u16)(r >> 16);
}

// packed f32x2 -> bf16x2 (RTNE), single instruction on gfx950
__device__ __forceinline__ u32 cvtpk(float lo, float hi) {
  u32 r;
  asm("v_cvt_pk_bf16_f32 %0, %1, %2" : "=v"(r) : "v"(lo), "v"(hi));
  return r;
}

__device__ __forceinline__ void gload_lds16(const void* g, void* l) {
  __builtin_amdgcn_global_load_lds((AS1 void*)(void*)g, (AS3 void*)l, 16, 0, 0);
}

__device__ __forceinline__ f32x4 mfma16(bf16x8 a, bf16x8 b, f32x4 c) {
  return __builtin_amdgcn_mfma_f32_16x16x32_bf16(a, b, c, 0, 0, 0);
}

// ---------------- fp32 -> bf16 convert, all three tensors in one launch ----------------
__global__ void k_f2bf3(const float* __restrict__ a, const float* __restrict__ bb,
                        const float* __restrict__ c, u16* __restrict__ oa,
                        u16* __restrict__ ob, u16* __restrict__ oc) {
  int i = blockIdx.x * blockDim.x + threadIdx.x;
  int stride = gridDim.x * blockDim.x;
  for (; i < 2097152; i += stride) {
    const float* src; u16* dst; int j = i;
    if (j < 1048576)      { src = a;  dst = oa; }
    else if (j < 1835008) { src = bb; dst = ob; j -= 1048576; }
    else                  { src = c;  dst = oc; j -= 1835008; }
    float4 v = reinterpret_cast<const float4*>(src)[j];
    ushort4 o;
    o.x = f2bf(v.x); o.y = f2bf(v.y); o.z = f2bf(v.z); o.w = f2bf(v.w);
    reinterpret_cast<ushort4*>(dst)[j] = o;
  }
}

// ---------------- GEMM: C[m][n] = A[m][:] . B[n][:] + bias[n] ----------------
// EPI 0 (qkv proj): cols<1024 -> bf16 out scaled by 0.125*log2e (q);
//                   cols in [1024,2048) -> bf16 out (k);
//                   cols>=2048 -> written ONLY to vt (transposed+permuted V).
// EPI 1: fp32 out + bias.
template<int BM, int BN, int EPI>
__global__ __launch_bounds__(256, 2)
void k_gemm_bt(const u16* __restrict__ A, const u16* __restrict__ B,
               const float* __restrict__ bias, void* __restrict__ out,
               u16* __restrict__ vt, int M, int N, int K)
{
  __shared__ __align__(16) u16 sA[BM * 32];
  __shared__ __align__(16) u16 sB[BN * 32];
  const int tid = threadIdx.x;
  const int lane = tid & 63;
  const int wid = tid >> 6;
  const int wm = wid >> 1, wn = wid & 1;
  const int bm0 = blockIdx.y * BM;
  const int bn0 = blockIdx.x * BN;
  constexpr int FM = BM / 32;
  constexpr int FN = BN / 32;

  f32x4 acc[FM][FN];
#pragma unroll
  for (int i = 0; i < FM; ++i)
#pragma unroll
    for (int j = 0; j < FN; ++j)
      acc[i][j] = (f32x4){0.f, 0.f, 0.f, 0.f};

  constexpr int CA = BM / 16;
  constexpr int CB = BN / 16;
  const int nk = K >> 5;
  for (int kt = 0; kt < nk; ++kt) {
    __syncthreads();
    const char* gA = (const char*)(A + (size_t)bm0 * K + kt * 32);
#pragma unroll
    for (int c = 0; c < CA / 4; ++c) {
      int ch = c * 4 + wid;
      int o = ch * 1024 + lane * 16;
      gload_lds16(gA + (size_t)(o >> 6) * (K * 2) + (o & 63), (char*)sA + ch * 1024);
    }
    const char* gB = (const char*)(B + (size_t)bn0 * K + kt * 32);
#pragma unroll
    for (int c = 0; c < CB / 4; ++c) {
      int ch = c * 4 + wid;
      int o = ch * 1024 + lane * 16;
      gload_lds16(gB + (size_t)(o >> 6) * (K * 2) + (o & 63), (char*)sB + ch * 1024);
    }
    __syncthreads();
    bf16x8 af[FM], bfr[FN];
#pragma unroll
    for (int mi = 0; mi < FM; ++mi) {
      int row = wm * (BM / 2) + mi * 16 + (lane & 15);
      af[mi] = *(const bf16x8*)((const char*)sA + row * 64 + ((lane >> 4) << 4));
    }
#pragma unroll
    for (int ni = 0; ni < FN; ++ni) {
      int row = wn * (BN / 2) + ni * 16 + (lane & 15);
      bfr[ni] = *(const bf16x8*)((const char*)sB + row * 64 + ((lane >> 4) << 4));
    }
#pragma unroll
    for (int mi = 0; mi < FM; ++mi)
#pragma unroll
      for (int ni = 0; ni < FN; ++ni)
        acc[mi][ni] = mfma16(af[mi], bfr[ni], acc[mi][ni]);
  }

#pragma unroll
  for (int mi = 0; mi < FM; ++mi)
#pragma unroll
    for (int ni = 0; ni < FN; ++ni) {
      int row = bm0 + wm * (BM / 2) + mi * 16 + ((lane >> 4) << 2);
      int col = bn0 + wn * (BN / 2) + ni * 16 + (lane & 15);
      float bv = bias[col];
      if (EPI == 0) {
        if (col < 2048) {
          float sc = (col < 1024) ? 0.18033688011112042f : 1.0f;  // 0.125*log2(e)
          u16* O = (u16*)out;
#pragma unroll
          for (int r = 0; r < 4; ++r)
            O[(size_t)(row + r) * N + col] = f2bf((acc[mi][ni][r] + bv) * sc);
        } else {
          // V: write transposed + column-permuted into vt[bh][d][t'] only.
          int hh = (col - 2048) >> 6, dd = (col - 2048) & 63;
          int bb = row >> 11;        // batch (rows 0..2047 -> 0, 2048..4095 -> 1)
          int t  = row & 2047;       // multiple of 4
          int g  = ((t >> 5) & 1) * 8 + (((t >> 2) & 3) << 1) + ((t >> 4) & 1);
          u16* dst = vt + (size_t)((bb * 16 + hh) * 64 + dd) * 2048 + ((t >> 6) << 6) + g * 4;
          uint2 w;
          w.x = cvtpk(acc[mi][ni][0] + bv, acc[mi][ni][1] + bv);
          w.y = cvtpk(acc[mi][ni][2] + bv, acc[mi][ni][3] + bv);
          *(uint2*)dst = w;
        }
      } else {
        float* O = (float*)out;
#pragma unroll
        for (int r = 0; r < 4; ++r)
          O[(size_t)(row + r) * N + col] = acc[mi][ni][r] + bv;
      }
    }
}

// ---------------- fused causal flash attention ----------------
// 64 q-rows per block (4 waves x 16 rows), swapped QK^T, in-register softmax,
// P packed via cvt_pk straight into PV B-fragments (permuted V). Grid 1024:
// bid pairs (u, u+512) get complementary qtiles for CU load balance.
__global__ __launch_bounds__(256, 4)
void k_attn(const u16* __restrict__ qkv, const u16* __restrict__ vt, u16* __restrict__ yb)
{
  __shared__ __align__(16) u16 sK[2][64 * 64];   // [kv][d], chunk-swizzled
  __shared__ __align__(16) u16 sV[2][64 * 64];   // [d][kv'] permuted V, chunk-swizzled
  const int tid = threadIdx.x;
  const int lane = tid & 63;
  const int wid = tid >> 6;
  const int bid = blockIdx.x;
  const int half = bid >> 9;
  const int u = bid & 511;
  const int bh = u >> 4;
  const int qs = u & 15;
  const int qtile = half ? (31 - qs) : qs;
  const int b = bh >> 4, h = bh & 15;
  const int q0 = qtile * 64;
  const int wq0 = q0 + wid * 16;
  const int l15 = lane & 15;
  const int l4 = lane >> 4;

  // Q fragment (B-operand of swapped QK^T): lane holds Q[q=wq0+l15][32ks+l4*8..]
  bf16x8 qf[2];
#pragma unroll
  for (int ks = 0; ks < 2; ++ks) {
    const u16* src = qkv + (size_t)(b * 2048 + wq0 + l15) * 3072 + h * 64 + ks * 32 + (l4 << 3);
    qf[ks] = *(const bf16x8*)src;
  }

  f32x4 oacc[4];   // y^T: [q=l15][d=di*16+l4*4+r]
  float m = -1e30f, lsum = 0.f;
#pragma unroll
  for (int di = 0; di < 4; ++di) oacc[di] = (f32x4){0.f, 0.f, 0.f, 0.f};

  auto stage = [&](int kv0, int buf) {
    const char* gK = (const char*)(qkv + (size_t)(b * 2048 + kv0) * 3072 + 1024 + h * 64);
    const char* gV = (const char*)(vt + (size_t)bh * 131072 + kv0);
#pragma unroll
    for (int i = 0; i < 2; ++i) {
      int ch = wid * 2 + i;
      int o = ch * 1024 + lane * 16;
      int row = o >> 7;
      int cs = ((o >> 4) & 7) ^ (row & 7);  // pre-swizzled global source chunk
      gload_lds16(gK + (size_t)row * 6144 + cs * 16, (char*)sK[buf] + ch * 1024);
      gload_lds16(gV + (size_t)row * 4096 + cs * 16, (char*)sV[buf] + ch * 1024);
    }
  };

  const int nt = qtile + 1;
  int cur = 0;
  stage(0, 0);
  __syncthreads();
  for (int t = 0; t < nt; ++t) {
    const int kv0 = t * 64;
    if (t + 1 < nt) stage((t + 1) * 64, cur ^ 1);  // prefetch next tile (drains at barrier)
    const bool active = (kv0 <= wq0 + 15);
    if (active) {
      // ---- QK^T (swapped): lane owns q=wq0+l15, kv=ki*16+l4*4+r
      f32x4 s[4];
#pragma unroll
      for (int ki = 0; ki < 4; ++ki) s[ki] = (f32x4){0.f, 0.f, 0.f, 0.f};
#pragma unroll
      for (int ks = 0; ks < 2; ++ks) {
        bf16x8 bk[4];
#pragma unroll
        for (int ki = 0; ki < 4; ++ki) {
          int row = ki * 16 + l15;
          int cc = (ks * 4 + l4) ^ (row & 7);
          bk[ki] = *(const bf16x8*)((const char*)sK[cur] + row * 128 + cc * 16);
        }
#pragma unroll
        for (int ki = 0; ki < 4; ++ki)
          s[ki] = mfma16(bk[ki], qf[ks], s[ki]);
      }
      if (kv0 + 63 > wq0) {  // causal mask (boundary tiles only)
        int qa = wq0 + l15;
#pragma unroll
        for (int ki = 0; ki < 4; ++ki) {
          int kvb = kv0 + ki * 16 + l4 * 4;
#pragma unroll
          for (int rr = 0; rr < 4; ++rr)
            if (kvb + rr > qa) s[ki][rr] = -1e30f;
        }
      }
      // ---- online softmax, per-lane row; defer-max (THR=8, log2 domain)
      float rm = s[0][0];
#pragma unroll
      for (int ki = 0; ki < 4; ++ki)
#pragma unroll
        for (int rr = 0; rr < 4; ++rr)
          rm = fmaxf(rm, s[ki][rr]);
      rm = fmaxf(rm, __shfl_xor(rm, 16));
      rm = fmaxf(rm, __shfl_xor(rm, 32));
      float mo = m;
      float mn;
      if (__all(rm <= mo + 8.f)) {
        mn = mo;  // stable: skip rescale, P bounded by 2^8
      } else {
        mn = fmaxf(mo, rm);
        float f = exp2f(mo - mn);
        m = mn;
        lsum *= f;
#pragma unroll
        for (int di = 0; di < 4; ++di)
#pragma unroll
          for (int rr = 0; rr < 4; ++rr)
            oacc[di][rr] *= f;
      }
      u32 pk_[4][2];
      float rs = 0.f;
#pragma unroll
      for (int ki = 0; ki < 4; ++ki) {
        float p0 = exp2f(s[ki][0] - mn);
        float p1 = exp2f(s[ki][1] - mn);
        float p2 = exp2f(s[ki][2] - mn);
        float p3 = exp2f(s[ki][3] - mn);
        rs += (p0 + p1) + (p2 + p3);
        pk_[ki][0] = cvtpk(p0, p1);
        pk_[ki][1] = cvtpk(p2, p3);
      }
      rs += __shfl_xor(rs, 16);
      rs += __shfl_xor(rs, 32);
      lsum += rs;
      // ---- PV: V column permutation makes k-index mapping match on both operands
#pragma unroll
      for (int ks = 0; ks < 2; ++ks) {
        u32x4 w0 = {pk_[2 * ks][0], pk_[2 * ks][1], pk_[2 * ks + 1][0], pk_[2 * ks + 1][1]};
        bf16x8 pb = __builtin_bit_cast(bf16x8, w0);
#pragma unroll
        for (int di = 0; di < 4; ++di) {
          int row = di * 16 + l15;
          int cc = (ks * 4 + l4) ^ (row & 7);
          bf16x8 bv = *(const bf16x8*)((const char*)sV[cur] + row * 128 + cc * 16);
          oacc[di] = mfma16(bv, pb, oacc[di]);
        }
      }
    }
    __syncthreads();  // drains vmcnt(0): publishes buf[cur^1] for next iteration
    cur ^= 1;
  }
  // ---- epilogue: normalize, pack 4 consecutive d per 8B store
  float inv = 1.f / lsum;
  size_t rowb = (size_t)(b * 2048 + wq0 + l15) * 1024 + h * 64 + l4 * 4;
#pragma unroll
  for (int di = 0; di < 4; ++di) {
    uint2 w;
    w.x = cvtpk(oacc[di][0] * inv, oacc[di][1] * inv);
    w.y = cvtpk(oacc[di][2] * inv, oacc[di][3] * inv);
    *(uint2*)(yb + rowb + di * 16) = w;
  }
}

extern "C" void kernel_launch(void* const* d_in, const int* in_sizes, int n_in,
                              void* d_out, int out_size, void* d_ws, size_t ws_size,
                              hipStream_t stream)
{
  (void)in_sizes; (void)n_in; (void)out_size; (void)ws_size;
  const float* x      = (const float*)d_in[0];
  const float* w_attn = (const float*)d_in[1];
  const float* b_attn = (const float*)d_in[2];
  const float* w_proj = (const float*)d_in[3];
  const float* b_proj = (const float*)d_in[4];
  float* out = (float*)d_out;
  char* ws = (char*)d_ws;
  u16* xb  = (u16*)(ws);                 // 4096x1024 bf16
  u16* wab = (u16*)(ws + 8388608);       // 3072x1024 bf16
  u16* wpb = (u16*)(ws + 14680064);      // 1024x1024 bf16
  u16* qkv = (u16*)(ws + 16777216);      // 4096x3072 bf16 (v region unused)
  u16* vt  = (u16*)(ws + 41943040);      // 32x64x2048 bf16 (permuted cols)
  u16* yb  = (u16*)(ws + 50331648);      // 4096x1024 bf16

  k_f2bf3<<<2048, 256, 0, stream>>>(x, w_attn, w_proj, xb, wab, wpb);
  k_gemm_bt<128, 128, 0><<<dim3(24, 32), 256, 0, stream>>>(xb, wab, b_attn, qkv, vt, 4096, 3072, 1024);
  k_attn<<<1024, 256, 0, stream>>>(qkv, vt, yb);
  k_gemm_bt<64, 128, 1><<<dim3(8, 64), 256, 0, stream>>>(yb, wpb, b_proj, out, nullptr, 4096, 1024, 1024);
}